// Round 4
// baseline (251.116 us; speedup 1.0000x reference)
//
#include <hip/hip_runtime.h>

// LIF scan over T=16: mem_t = beta*mem + x_t - spk_{t-1}; spk_t = (mem_t - 1) > 0.
// Neurons independent -> 1 thread owns 4 neurons across all T.
// R4: R3's prefetch burst was silently undone by the compiler's pressure-aware
// scheduler (VGPR=36 proves loads were re-sunk next to uses -> ~2 in flight).
// Fix: __builtin_amdgcn_sched_barrier(0) after the load loop pins all 16
// global_load_dwordx4 before any compute; compute then drains at vmcnt(15..0)
// with stores overlapping the remaining load latency.

constexpr int   T      = 16;
constexpr float BETA   = 0.9f;
constexpr float THRESH = 1.0f;

typedef float f4 __attribute__((ext_vector_type(4)));

__global__ __launch_bounds__(256) void lif_kernel(const float* __restrict__ x,
                                                  float* __restrict__ out,
                                                  int n_per_t) {
    // No FMA contraction: must match numpy's two-rounding fp32 exactly, else
    // ~1-ulp drift flips spikes at the threshold (absmax = 1.0 cascades).
#pragma clang fp contract(off)
    const int idx = (blockIdx.x * blockDim.x + threadIdx.x) * 4;
    if (idx >= n_per_t) return;

    f4 v[T];  // load burst results (64 VGPRs) — intentionally live all at once

    // Phase 1: issue all 16 loads back-to-back (1 KB/wave each, coalesced).
#pragma unroll
    for (int t = 0; t < T; ++t) {
        v[t] = *reinterpret_cast<const f4*>(x + (size_t)t * (size_t)n_per_t + (size_t)idx);
    }
    // Hard scheduling fence: nothing may cross. Keeps the 16 loads issued
    // as a burst instead of being sunk to their uses.
    __builtin_amdgcn_sched_barrier(0);

    // Phase 2+3: recurrence; store spk_t immediately (fire-and-forget) so
    // stores overlap the still-in-flight tail loads.
    f4 mem = (f4)(0.f);
    f4 spk = (f4)(0.f);
#pragma unroll
    for (int t = 0; t < T; ++t) {
#pragma unroll
        for (int j = 0; j < 4; ++j) {
            mem[j] = BETA * mem[j] + v[t][j] - spk[j] * THRESH;
            spk[j] = (mem[j] - THRESH) > 0.f ? 1.f : 0.f;
        }
        __builtin_nontemporal_store(spk,
            reinterpret_cast<f4*>(out + (size_t)t * (size_t)n_per_t + (size_t)idx));
    }
}

extern "C" void kernel_launch(void* const* d_in, const int* in_sizes, int n_in,
                              void* d_out, int out_size, void* d_ws, size_t ws_size,
                              hipStream_t stream) {
    const float* x   = (const float*)d_in[0];
    float*       out = (float*)d_out;

    const int total   = in_sizes[0];      // 33,554,432
    const int n_per_t = total / T;        // 2,097,152 (divisible by 4)
    const int threads = n_per_t / 4;      // 524,288

    dim3 block(256);
    dim3 grid((threads + block.x - 1) / block.x);  // 2048 blocks
    lif_kernel<<<grid, block, 0, stream>>>(x, out, n_per_t);
}

// Round 6
// 245.824 us; speedup vs baseline: 1.0215x; 1.0215x over previous
//
#include <hip/hip_runtime.h>

// LIF scan over T=16: mem_t = beta*mem + x_t - spk_{t-1}; spk_t = (mem_t - 1) > 0.
// One thread owns 4 neurons (float4) across all T.
// History: R1/R3/R4 ~2 TB/s, VGPR=36 — compiler re-sinks register prefetch, ~1-2
// loads in flight/wave (latency-bound). R5 register-landing via inline asm
// miscompiled (RA copies around tied waitcnt).
// R6: burst via async global->LDS DMA. __builtin_amdgcn_global_load_lds lands
// data in LDS (no VGPR hazard, compiler can't re-sink a side-effecting DMA).
// 16 x 16B per thread = 16 KB/wave in flight; vmcnt retires in issue order, so
// s_waitcnt vmcnt(15) before step t guarantees loads 0..t landed while keeping
// ~15 vmem ops outstanding continuously.

constexpr int   T      = 16;
constexpr float BETA   = 0.9f;
constexpr float THRESH = 1.0f;

typedef float f4 __attribute__((ext_vector_type(4)));

__global__ __launch_bounds__(256) void lif_kernel(const float* __restrict__ x,
                                                  float* __restrict__ out,
                                                  int n_per_t) {
    // No FMA contraction: must match numpy's two-rounding fp32 exactly, else
    // ~1-ulp drift flips spikes at the threshold (absmax = 1.0 cascades).
#pragma clang fp contract(off)
    __shared__ float lds[T * 256 * 4];  // 64 KB: slot (t, wave, lane) = 16 B

    const int    tid  = threadIdx.x;
    const int    wave = tid >> 6;   // wave-uniform
    const int    lane = tid & 63;
    const size_t np   = (size_t)n_per_t;
    const size_t goff = (size_t)(blockIdx.x * 256 + tid) * 4;  // 4 floats/thread/t

    // Phase 1: 16 async DMA loads, fire-and-forget. LDS dest is wave-uniform
    // base; hardware lands lane i at base + i*16B (m104/m108 semantics).
#pragma unroll
    for (int t = 0; t < T; ++t) {
        const float* gsrc = x + (size_t)t * np + goff;
        float*       ldst = &lds[(t * 4 + wave) * 256];  // wave-uniform base
        __builtin_amdgcn_global_load_lds(
            (const __attribute__((address_space(1))) void*)gsrc,
            (__attribute__((address_space(3))) void*)ldst,
            16, 0, 0);
    }

    // Phase 2: incremental drain. vmcnt ops retire in issue order; before step
    // t we have issued 16 loads + t stores, so waiting vmcnt(15) forces >= t+1
    // retirements => loads 0..t are in LDS. Each thread reads only its own
    // wave's slots, so no __syncthreads needed.
    f4 mem = (f4)(0.f);
    f4 spk = (f4)(0.f);

#pragma unroll
    for (int t = 0; t < T; ++t) {
        asm volatile("s_waitcnt vmcnt(15)" ::: "memory");
        const f4 xt = *reinterpret_cast<const f4*>(&lds[((t * 4 + wave) * 64 + lane) * 4]);
#pragma unroll
        for (int j = 0; j < 4; ++j) {
            mem[j] = BETA * mem[j] + xt[j] - spk[j] * THRESH;
            spk[j] = (mem[j] - THRESH) > 0.f ? 1.f : 0.f;
        }
        __builtin_nontemporal_store(spk,
            reinterpret_cast<f4*>(out + (size_t)t * np + goff));
    }
}

extern "C" void kernel_launch(void* const* d_in, const int* in_sizes, int n_in,
                              void* d_out, int out_size, void* d_ws, size_t ws_size,
                              hipStream_t stream) {
    const float* x   = (const float*)d_in[0];
    float*       out = (float*)d_out;

    const int total   = in_sizes[0];      // 33,554,432
    const int n_per_t = total / T;        // 2,097,152
    const int threads = n_per_t / 4;      // 524,288

    dim3 block(256);
    dim3 grid((threads + block.x - 1) / block.x);  // 2048 blocks
    lif_kernel<<<grid, block, 0, stream>>>(x, out, n_per_t);
}